// Round 2
// baseline (725.475 us; speedup 1.0000x reference)
//
#include <hip/hip_runtime.h>
#include <stdint.h>

// Problem constants
#define BB 8
#define TT 4096
#define HH 1024
#define SS 64
#define NHH 16
#define DHH 64

typedef __attribute__((ext_vector_type(8))) short short8;
typedef __attribute__((ext_vector_type(8))) unsigned short ushortx8;
typedef __attribute__((ext_vector_type(4))) float f32x4;
typedef unsigned short u16;

__device__ __forceinline__ u16 f2bf(float f) {
  union { float f; uint32_t u; } v;
  v.f = f;
  uint32_t u = v.u;
  uint32_t r = u + 0x7fffu + ((u >> 16) & 1u);
  return (u16)(r >> 16);
}

// Stage a 128-row x 64-col f32 tile (row stride ld) into swizzled bf16 LDS.
// LDS layout: row*64 + (slot ^ (row&7))*8, slot = k/8 (8 slots of 8 bf16 = 16B).
__device__ __forceinline__ void stage_tile(u16* lds, const float* src, int ld, int tid) {
#pragma unroll
  for (int q = 0; q < 4; ++q) {
    int slot_id = tid + (q << 8);
    int row = slot_id >> 3;
    int sl = slot_id & 7;
    const float* p = src + (size_t)row * ld + (sl << 3);
    float4 x0 = *(const float4*)(p);
    float4 x1 = *(const float4*)(p + 4);
    ushortx8 o;
    o[0] = f2bf(x0.x); o[1] = f2bf(x0.y); o[2] = f2bf(x0.z); o[3] = f2bf(x0.w);
    o[4] = f2bf(x1.x); o[5] = f2bf(x1.y); o[6] = f2bf(x1.z); o[7] = f2bf(x1.w);
    *(ushortx8*)(&lds[(row << 6) + (((sl ^ (row & 7)) << 3))]) = o;
  }
}

// ---------------- K1: sentence mean pooling ----------------
__global__ __launch_bounds__(256) void pool_kernel(const float* __restrict__ h,
                                                   const int* __restrict__ bounds,
                                                   float* __restrict__ sent) {
  int bs = blockIdx.x;           // b*64 + s
  int b = bs >> 6;
  int start = bounds[bs * 2];
  int end = bounds[bs * 2 + 1];
  int lo = max(start, 0), hi = min(end, TT);
  int cnt = max(hi - lo, 0);
  float inv = 1.0f / (float)max(cnt, 1);
  for (int col = threadIdx.x; col < HH; col += 256) {
    float a = 0.f;
    for (int t = lo; t < hi; ++t) a += h[((size_t)b * TT + t) * HH + col];
    sent[(size_t)bs * HH + col] = a * inv;
  }
}

// ---------------- K2: sentence id per token ----------------
__global__ __launch_bounds__(256) void sid_kernel(const int* __restrict__ bounds,
                                                  int* __restrict__ sid) {
  int idx = blockIdx.x * 256 + threadIdx.x;  // B*T
  if (idx >= BB * TT) return;
  int b = idx >> 12, t = idx & (TT - 1);
  int r = -1;
  for (int s = 0; s < SS; ++s) {
    int st = bounds[(b * SS + s) * 2], en = bounds[(b * SS + s) * 2 + 1];
    if (t >= st && t < en) { r = s; break; }
  }
  sid[idx] = r;
}

// ---------------- generic C = A @ B^T + bias (bf16 MFMA) ----------------
// Tile 128x128, BK=64, 256 threads (4 waves 2x2, each 64x64).
__global__ __launch_bounds__(256) void gemm_bt_bias(const float* __restrict__ A, int lda,
                                                    const float* __restrict__ Bm, int ldb,
                                                    const float* __restrict__ bias,
                                                    float* __restrict__ C, int ldc, int K) {
  __shared__ u16 As[128 * 64];
  __shared__ u16 Bs[128 * 64];
  int tid = threadIdx.x;
  int m0 = blockIdx.x * 128, n0 = blockIdx.y * 128;
  f32x4 acc[4][4] = {};

  for (int k0 = 0; k0 < K; k0 += 64) {
    __syncthreads();
    stage_tile(As, A + (size_t)m0 * lda + k0, lda, tid);
    stage_tile(Bs, Bm + (size_t)n0 * ldb + k0, ldb, tid);
    __syncthreads();
    int lane = tid & 63, wid = tid >> 6;
    int wm = wid >> 1, wn = wid & 1;
    int lr = lane & 15, lg = lane >> 4;
#pragma unroll
    for (int kk = 0; kk < 2; ++kk) {
      short8 af[4], bfr[4];
#pragma unroll
      for (int i = 0; i < 4; ++i) {
        int arow = wm * 64 + i * 16 + lr;
        int aslot = (kk * 4 + lg) ^ (arow & 7);
        af[i] = *(const short8*)(&As[(arow << 6) + (aslot << 3)]);
        int brow = wn * 64 + i * 16 + lr;
        int bslot = (kk * 4 + lg) ^ (brow & 7);
        bfr[i] = *(const short8*)(&Bs[(brow << 6) + (bslot << 3)]);
      }
#pragma unroll
      for (int i = 0; i < 4; ++i)
#pragma unroll
        for (int j = 0; j < 4; ++j)
          acc[i][j] = __builtin_amdgcn_mfma_f32_16x16x32_bf16(af[i], bfr[j], acc[i][j], 0, 0, 0);
    }
  }

  int lane = tid & 63, wid = tid >> 6;
  int wm = wid >> 1, wn = wid & 1;
  int lr = lane & 15, lg = lane >> 4;
#pragma unroll
  for (int i = 0; i < 4; ++i)
#pragma unroll
    for (int j = 0; j < 4; ++j)
#pragma unroll
      for (int r = 0; r < 4; ++r) {
        int row = m0 + wm * 64 + i * 16 + lg * 4 + r;
        int col = n0 + wn * 64 + j * 16 + lr;
        C[(size_t)row * ldc + col] = acc[i][j][r] + bias[col];
      }
}

// ---------------- K4: attention over S=64 per (b, head) ----------------
__global__ __launch_bounds__(256) void attn_kernel(const float* __restrict__ qkv,
                                                   float* __restrict__ ctx) {
  int bh = blockIdx.x;
  int b = bh >> 4, nh = bh & 15;
  __shared__ float q[64][64], k[64][64], v[64][64], s[64][64];
  int tid = threadIdx.x;
  const float* base = qkv + (size_t)b * SS * 3072 + nh * 64;
  for (int e = tid; e < 4096; e += 256) {
    int i = e >> 6, d = e & 63;
    q[i][d] = base[(size_t)i * 3072 + d];
    k[i][d] = base[(size_t)i * 3072 + 1024 + d];
    v[i][d] = base[(size_t)i * 3072 + 2048 + d];
  }
  __syncthreads();
  for (int e = tid; e < 4096; e += 256) {
    int i = e >> 6, j = e & 63;
    float acc = 0.f;
#pragma unroll 8
    for (int d = 0; d < 64; ++d) acc += q[i][d] * k[j][d];
    s[i][j] = acc * 0.125f;  // 1/sqrt(64)
  }
  __syncthreads();
  if (tid < 64) {
    float m = -1e30f;
    for (int j = 0; j < 64; ++j) m = fmaxf(m, s[tid][j]);
    float sum = 0.f;
    for (int j = 0; j < 64; ++j) { float e_ = __expf(s[tid][j] - m); s[tid][j] = e_; sum += e_; }
    float inv = 1.0f / sum;
    for (int j = 0; j < 64; ++j) s[tid][j] *= inv;
  }
  __syncthreads();
  for (int e = tid; e < 4096; e += 256) {
    int i = e >> 6, d = e & 63;
    float acc = 0.f;
#pragma unroll 8
    for (int j = 0; j < 64; ++j) acc += s[i][j] * v[j][d];
    ctx[((size_t)b * SS + i) * HH + nh * 64 + d] = acc;
  }
}

// ---------------- K7: fused u = h@w1a^T, score, out = h*(1+score) ----------------
__global__ __launch_bounds__(256) void fused_score_out(const float* __restrict__ h,
                                                       const float* __restrict__ cbuf,
                                                       const float* __restrict__ w1,
                                                       const float* __restrict__ w2,
                                                       const float* __restrict__ b2,
                                                       const int* __restrict__ sid_arr,
                                                       float* __restrict__ out) {
  __shared__ u16 As[128 * 64];
  __shared__ u16 Bs[128 * 64];
  __shared__ float w2_lds[1024];
  __shared__ int sid_lds[128];
  __shared__ float red[128];

  int tid = threadIdx.x;
  size_t g0 = (size_t)blockIdx.x * 128;  // global token row
  int b = (int)(g0 >> 12);               // / T
  const float* hblk = h + g0 * HH;

  for (int i = tid; i < 1024; i += 256) w2_lds[i] = w2[i];
  if (tid < 128) {
    sid_lds[tid] = sid_arr[g0 + tid];
    red[tid] = 0.f;
  }

  int lane = tid & 63, wid = tid >> 6;
  int wm = wid >> 1, wn = wid & 1;
  int lr = lane & 15, lg = lane >> 4;

  float sp[4][4] = {};  // per-lane partial scores [mfrag][reg]

  for (int chunk = 0; chunk < 8; ++chunk) {
    f32x4 acc[4][4] = {};
    int n0 = chunk * 128;
    for (int k0 = 0; k0 < 1024; k0 += 64) {
      __syncthreads();
      stage_tile(As, hblk + k0, HH, tid);
      stage_tile(Bs, w1 + (size_t)n0 * 2048 + k0, 2048, tid);
      __syncthreads();
#pragma unroll
      for (int kk = 0; kk < 2; ++kk) {
        short8 af[4], bfr[4];
#pragma unroll
        for (int i = 0; i < 4; ++i) {
          int arow = wm * 64 + i * 16 + lr;
          int aslot = (kk * 4 + lg) ^ (arow & 7);
          af[i] = *(const short8*)(&As[(arow << 6) + (aslot << 3)]);
          int brow = wn * 64 + i * 16 + lr;
          int bslot = (kk * 4 + lg) ^ (brow & 7);
          bfr[i] = *(const short8*)(&Bs[(brow << 6) + (bslot << 3)]);
        }
#pragma unroll
        for (int i = 0; i < 4; ++i)
#pragma unroll
          for (int j = 0; j < 4; ++j)
            acc[i][j] = __builtin_amdgcn_mfma_f32_16x16x32_bf16(af[i], bfr[j], acc[i][j], 0, 0, 0);
      }
    }
    // score epilogue for this N-chunk
#pragma unroll
    for (int i = 0; i < 4; ++i) {
#pragma unroll
      for (int r = 0; r < 4; ++r) {
        int rowl = wm * 64 + i * 16 + lg * 4 + r;
        int s = sid_lds[rowl];
        int sc = s < 0 ? 0 : s;
        const float* crow = cbuf + ((size_t)b * SS + sc) * HH + n0;
        float accs = 0.f;
#pragma unroll
        for (int j = 0; j < 4; ++j) {
          int coll = wn * 64 + j * 16 + lr;
          float t = acc[i][j][r] + crow[coll];
          if (t > 0.f) accs += t * w2_lds[n0 + coll];
        }
        sp[i][r] += accs;
      }
    }
  }

  // reduce partial scores across the 16 lanes of each lane-group
#pragma unroll
  for (int i = 0; i < 4; ++i)
#pragma unroll
    for (int r = 0; r < 4; ++r) {
      float v = sp[i][r];
      v += __shfl_xor(v, 1);
      v += __shfl_xor(v, 2);
      v += __shfl_xor(v, 4);
      v += __shfl_xor(v, 8);
      sp[i][r] = v;
    }
  if (lr == 0) {
#pragma unroll
    for (int i = 0; i < 4; ++i)
#pragma unroll
      for (int r = 0; r < 4; ++r)
        atomicAdd(&red[wm * 64 + i * 16 + lg * 4 + r], sp[i][r]);
  }
  __syncthreads();
  if (tid < 128) {
    int s = sid_lds[tid];
    float sc = (s >= 0) ? (red[tid] + b2[0]) : 0.f;
    red[tid] = 1.0f + sc;  // multiplier
  }
  __syncthreads();

  // out = h * factor
  const float4* h4 = (const float4*)(hblk);
  float4* o4 = (float4*)(out + g0 * HH);
  for (int e = tid; e < 128 * 256; e += 256) {
    int row = e >> 8;
    float f = red[row];
    float4 vv = h4[e];
    vv.x *= f; vv.y *= f; vv.z *= f; vv.w *= f;
    o4[e] = vv;
  }
}

extern "C" void kernel_launch(void* const* d_in, const int* in_sizes, int n_in,
                              void* d_out, int out_size, void* d_ws, size_t ws_size,
                              hipStream_t stream) {
  const float* h        = (const float*)d_in[0];
  const int*   bounds   = (const int*)d_in[1];
  const float* in_proj_w = (const float*)d_in[2];
  const float* in_proj_b = (const float*)d_in[3];
  const float* out_w    = (const float*)d_in[4];
  const float* out_b    = (const float*)d_in[5];
  const float* w1       = (const float*)d_in[6];
  const float* b1       = (const float*)d_in[7];
  const float* w2       = (const float*)d_in[8];
  const float* b2       = (const float*)d_in[9];
  float* out = (float*)d_out;

  char* ws = (char*)d_ws;
  float* sent = (float*)(ws);                         // 512*1024 f32 = 2 MB
  float* qkv  = (float*)(ws + (2ull << 20));          // 512*3072 f32 = 6 MB
  float* ctx  = (float*)(ws + (8ull << 20));          // 2 MB
  float* att  = (float*)(ws + (10ull << 20));         // 2 MB
  float* cbuf = (float*)(ws + (12ull << 20));         // 2 MB
  int*   sid  = (int*)(ws + (14ull << 20));           // 128 KB

  pool_kernel<<<BB * SS, 256, 0, stream>>>(h, bounds, sent);
  sid_kernel<<<(BB * TT) / 256, 256, 0, stream>>>(bounds, sid);
  // qkv = sent @ in_proj_w^T + in_proj_b   (512 x 3072, K=1024)
  gemm_bt_bias<<<dim3(4, 24), 256, 0, stream>>>(sent, HH, in_proj_w, HH, in_proj_b, qkv, 3 * HH, HH);
  attn_kernel<<<BB * NHH, 256, 0, stream>>>(qkv, ctx);
  // attended = ctx @ out_w^T + out_b       (512 x 1024, K=1024)
  gemm_bt_bias<<<dim3(4, 8), 256, 0, stream>>>(ctx, HH, out_w, HH, out_b, att, HH, HH);
  // c = attended @ w1b^T + b1              (512 x 1024, K=1024), w1b = w1[:, H:]
  gemm_bt_bias<<<dim3(4, 8), 256, 0, stream>>>(att, HH, w1 + HH, 2 * HH, b1, cbuf, HH, HH);
  // fused big GEMM + score + output
  fused_score_out<<<(BB * TT) / 128, 256, 0, stream>>>(h, cbuf, w1, w2, b2, sid, out);
}

// Round 3
// 515.211 us; speedup vs baseline: 1.4081x; 1.4081x over previous
//
#include <hip/hip_runtime.h>
#include <stdint.h>

// Problem constants
#define BB 8
#define TT 4096
#define HH 1024
#define SS 64
#define NHH 16
#define DHH 64

typedef __attribute__((ext_vector_type(8))) short short8;
typedef __attribute__((ext_vector_type(8))) unsigned short ushortx8;
typedef __attribute__((ext_vector_type(4))) float f32x4;
typedef unsigned short u16;

__device__ __forceinline__ u16 f2bf(float f) {
  union { float f; uint32_t u; } v;
  v.f = f;
  uint32_t u = v.u;
  uint32_t r = u + 0x7fffu + ((u >> 16) & 1u);
  return (u16)(r >> 16);
}

// Stage a 128-row x 64-col f32 tile (row stride ld) into swizzled bf16 LDS.
// LDS layout: row*64 + (slot ^ (row&7))*8, slot = k/8 (8 slots of 8 bf16 = 16B).
__device__ __forceinline__ void stage_tile(u16* lds, const float* src, int ld, int tid) {
#pragma unroll
  for (int q = 0; q < 4; ++q) {
    int slot_id = tid + (q << 8);
    int row = slot_id >> 3;
    int sl = slot_id & 7;
    const float* p = src + (size_t)row * ld + (sl << 3);
    float4 x0 = *(const float4*)(p);
    float4 x1 = *(const float4*)(p + 4);
    ushortx8 o;
    o[0] = f2bf(x0.x); o[1] = f2bf(x0.y); o[2] = f2bf(x0.z); o[3] = f2bf(x0.w);
    o[4] = f2bf(x1.x); o[5] = f2bf(x1.y); o[6] = f2bf(x1.z); o[7] = f2bf(x1.w);
    *(ushortx8*)(&lds[(row << 6) + (((sl ^ (row & 7)) << 3))]) = o;
  }
}

// ---------------- K1: sentence mean pooling (float4 + 4 accumulators) ----------------
__global__ __launch_bounds__(256) void pool_kernel(const float* __restrict__ h,
                                                   const int* __restrict__ bounds,
                                                   float* __restrict__ sent) {
  int bs = blockIdx.x;           // b*64 + s
  int b = bs >> 6;
  int start = bounds[bs * 2];
  int end = bounds[bs * 2 + 1];
  int lo = max(start, 0), hi = min(end, TT);
  int cnt = max(hi - lo, 0);
  float inv = 1.0f / (float)max(cnt, 1);
  int tid = threadIdx.x;  // one float4 column group per thread
  const float4* h4 = (const float4*)(h) + (size_t)b * TT * 256 + tid;
  float4 a0 = {0, 0, 0, 0}, a1 = {0, 0, 0, 0}, a2 = {0, 0, 0, 0}, a3 = {0, 0, 0, 0};
  int t = lo;
  for (; t + 4 <= hi; t += 4) {
    float4 v0 = h4[(size_t)(t + 0) * 256];
    float4 v1 = h4[(size_t)(t + 1) * 256];
    float4 v2 = h4[(size_t)(t + 2) * 256];
    float4 v3 = h4[(size_t)(t + 3) * 256];
    a0.x += v0.x; a0.y += v0.y; a0.z += v0.z; a0.w += v0.w;
    a1.x += v1.x; a1.y += v1.y; a1.z += v1.z; a1.w += v1.w;
    a2.x += v2.x; a2.y += v2.y; a2.z += v2.z; a2.w += v2.w;
    a3.x += v3.x; a3.y += v3.y; a3.z += v3.z; a3.w += v3.w;
  }
  for (; t < hi; ++t) {
    float4 v0 = h4[(size_t)t * 256];
    a0.x += v0.x; a0.y += v0.y; a0.z += v0.z; a0.w += v0.w;
  }
  float4 r;
  r.x = (a0.x + a1.x + a2.x + a3.x) * inv;
  r.y = (a0.y + a1.y + a2.y + a3.y) * inv;
  r.z = (a0.z + a1.z + a2.z + a3.z) * inv;
  r.w = (a0.w + a1.w + a2.w + a3.w) * inv;
  ((float4*)sent)[(size_t)bs * 256 + tid] = r;
}

// ---------------- K2: sentence id per token ----------------
__global__ __launch_bounds__(256) void sid_kernel(const int* __restrict__ bounds,
                                                  int* __restrict__ sid) {
  int idx = blockIdx.x * 256 + threadIdx.x;  // B*T
  if (idx >= BB * TT) return;
  int b = idx >> 12, t = idx & (TT - 1);
  int r = -1;
  for (int s = 0; s < SS; ++s) {
    int st = bounds[(b * SS + s) * 2], en = bounds[(b * SS + s) * 2 + 1];
    if (t >= st && t < en) { r = s; break; }
  }
  sid[idx] = r;
}

// ---------------- generic C = A @ B^T + bias (bf16 MFMA) ----------------
// Tile 128x128, BK=64, 256 threads (4 waves 2x2, each 64x64).
__global__ __launch_bounds__(256) void gemm_bt_bias(const float* __restrict__ A, int lda,
                                                    const float* __restrict__ Bm, int ldb,
                                                    const float* __restrict__ bias,
                                                    float* __restrict__ C, int ldc, int K) {
  __shared__ u16 As[128 * 64];
  __shared__ u16 Bs[128 * 64];
  int tid = threadIdx.x;
  int m0 = blockIdx.x * 128, n0 = blockIdx.y * 128;
  f32x4 acc[4][4] = {};

  for (int k0 = 0; k0 < K; k0 += 64) {
    __syncthreads();
    stage_tile(As, A + (size_t)m0 * lda + k0, lda, tid);
    stage_tile(Bs, Bm + (size_t)n0 * ldb + k0, ldb, tid);
    __syncthreads();
    int lane = tid & 63, wid = tid >> 6;
    int wm = wid >> 1, wn = wid & 1;
    int lr = lane & 15, lg = lane >> 4;
#pragma unroll
    for (int kk = 0; kk < 2; ++kk) {
      short8 af[4], bfr[4];
#pragma unroll
      for (int i = 0; i < 4; ++i) {
        int arow = wm * 64 + i * 16 + lr;
        int aslot = (kk * 4 + lg) ^ (arow & 7);
        af[i] = *(const short8*)(&As[(arow << 6) + (aslot << 3)]);
        int brow = wn * 64 + i * 16 + lr;
        int bslot = (kk * 4 + lg) ^ (brow & 7);
        bfr[i] = *(const short8*)(&Bs[(brow << 6) + (bslot << 3)]);
      }
#pragma unroll
      for (int i = 0; i < 4; ++i)
#pragma unroll
        for (int j = 0; j < 4; ++j)
          acc[i][j] = __builtin_amdgcn_mfma_f32_16x16x32_bf16(af[i], bfr[j], acc[i][j], 0, 0, 0);
    }
  }

  int lane = tid & 63, wid = tid >> 6;
  int wm = wid >> 1, wn = wid & 1;
  int lr = lane & 15, lg = lane >> 4;
#pragma unroll
  for (int i = 0; i < 4; ++i)
#pragma unroll
    for (int j = 0; j < 4; ++j)
#pragma unroll
      for (int r = 0; r < 4; ++r) {
        int row = m0 + wm * 64 + i * 16 + lg * 4 + r;
        int col = n0 + wn * 64 + j * 16 + lr;
        C[(size_t)row * ldc + col] = acc[i][j][r] + bias[col];
      }
}

// ---------------- K4: attention over S=64 per (b, head) ----------------
__global__ __launch_bounds__(256) void attn_kernel(const float* __restrict__ qkv,
                                                   float* __restrict__ ctx) {
  int bh = blockIdx.x;
  int b = bh >> 4, nh = bh & 15;
  __shared__ float q[64][64], k[64][64], v[64][64], s[64][64];
  int tid = threadIdx.x;
  const float* base = qkv + (size_t)b * SS * 3072 + nh * 64;
  for (int e = tid; e < 4096; e += 256) {
    int i = e >> 6, d = e & 63;
    q[i][d] = base[(size_t)i * 3072 + d];
    k[i][d] = base[(size_t)i * 3072 + 1024 + d];
    v[i][d] = base[(size_t)i * 3072 + 2048 + d];
  }
  __syncthreads();
  for (int e = tid; e < 4096; e += 256) {
    int i = e >> 6, j = e & 63;
    float acc = 0.f;
#pragma unroll 8
    for (int d = 0; d < 64; ++d) acc += q[i][d] * k[j][d];
    s[i][j] = acc * 0.125f;  // 1/sqrt(64)
  }
  __syncthreads();
  if (tid < 64) {
    float m = -1e30f;
    for (int j = 0; j < 64; ++j) m = fmaxf(m, s[tid][j]);
    float sum = 0.f;
    for (int j = 0; j < 64; ++j) { float e_ = __expf(s[tid][j] - m); s[tid][j] = e_; sum += e_; }
    float inv = 1.0f / sum;
    for (int j = 0; j < 64; ++j) s[tid][j] *= inv;
  }
  __syncthreads();
  for (int e = tid; e < 4096; e += 256) {
    int i = e >> 6, d = e & 63;
    float acc = 0.f;
#pragma unroll 8
    for (int j = 0; j < 64; ++j) acc += s[i][j] * v[j][d];
    ctx[((size_t)b * SS + i) * HH + nh * 64 + d] = acc;
  }
}

// ---------------- K7: partial score for one (M-tile, N-chunk) ----------------
// grid: 2048 blocks; m = bid>>3 (M-tile of 128 rows), c = bid&7 (N-chunk of 128 cols).
// Default XCD round-robin => chunk c lands on XCD c%8: each XCD's w1-slice stays L2-hot.
__global__ __launch_bounds__(256) void score_partial(const float* __restrict__ h,
                                                     const float* __restrict__ cbuf,
                                                     const float* __restrict__ w1,
                                                     const float* __restrict__ w2,
                                                     const int* __restrict__ sid_arr,
                                                     float* __restrict__ score_part) {
  __shared__ u16 As[128 * 64];
  __shared__ u16 Bs[128 * 64];
  __shared__ float w2_lds[128];
  __shared__ int sid_lds[128];
  __shared__ float red[128];

  int tid = threadIdx.x;
  int bid = blockIdx.x;
  int mt = bid >> 3;
  int c = bid & 7;
  int n0 = c * 128;
  size_t g0 = (size_t)mt * 128;  // global token row
  int b = (int)(g0 >> 12);       // / T
  const float* hblk = h + g0 * HH;

  if (tid < 128) {
    w2_lds[tid] = w2[n0 + tid];
    sid_lds[tid] = sid_arr[g0 + tid];
    red[tid] = 0.f;
  }

  int lane = tid & 63, wid = tid >> 6;
  int wm = wid >> 1, wn = wid & 1;
  int lr = lane & 15, lg = lane >> 4;

  f32x4 acc[4][4] = {};
  for (int k0 = 0; k0 < 1024; k0 += 64) {
    __syncthreads();
    stage_tile(As, hblk + k0, HH, tid);
    stage_tile(Bs, w1 + (size_t)n0 * 2048 + k0, 2048, tid);
    __syncthreads();
#pragma unroll
    for (int kk = 0; kk < 2; ++kk) {
      short8 af[4], bfr[4];
#pragma unroll
      for (int i = 0; i < 4; ++i) {
        int arow = wm * 64 + i * 16 + lr;
        int aslot = (kk * 4 + lg) ^ (arow & 7);
        af[i] = *(const short8*)(&As[(arow << 6) + (aslot << 3)]);
        int brow = wn * 64 + i * 16 + lr;
        int bslot = (kk * 4 + lg) ^ (brow & 7);
        bfr[i] = *(const short8*)(&Bs[(brow << 6) + (bslot << 3)]);
      }
#pragma unroll
      for (int i = 0; i < 4; ++i)
#pragma unroll
        for (int j = 0; j < 4; ++j)
          acc[i][j] = __builtin_amdgcn_mfma_f32_16x16x32_bf16(af[i], bfr[j], acc[i][j], 0, 0, 0);
    }
  }

  // score epilogue: sp = sum_j w2[j] * relu(u + c[sid, j]) over this chunk's 128 cols
  float sp[4][4];
#pragma unroll
  for (int i = 0; i < 4; ++i) {
#pragma unroll
    for (int r = 0; r < 4; ++r) {
      int rowl = wm * 64 + i * 16 + lg * 4 + r;
      int s = sid_lds[rowl];
      int sc = s < 0 ? 0 : s;
      const float* crow = cbuf + ((size_t)b * SS + sc) * HH + n0;
      float accs = 0.f;
#pragma unroll
      for (int j = 0; j < 4; ++j) {
        int coll = wn * 64 + j * 16 + lr;
        float t = acc[i][j][r] + crow[coll];
        if (t > 0.f) accs += t * w2_lds[coll];
      }
      sp[i][r] = accs;
    }
  }

  // reduce across the 16 lanes of each lane-group
#pragma unroll
  for (int i = 0; i < 4; ++i)
#pragma unroll
    for (int r = 0; r < 4; ++r) {
      float v = sp[i][r];
      v += __shfl_xor(v, 1);
      v += __shfl_xor(v, 2);
      v += __shfl_xor(v, 4);
      v += __shfl_xor(v, 8);
      sp[i][r] = v;
    }
  if (lr == 0) {
#pragma unroll
    for (int i = 0; i < 4; ++i)
#pragma unroll
      for (int r = 0; r < 4; ++r)
        atomicAdd(&red[wm * 64 + i * 16 + lg * 4 + r], sp[i][r]);
  }
  __syncthreads();
  if (tid < 128) score_part[(size_t)c * (BB * TT) + g0 + tid] = red[tid];
}

// ---------------- K8: factor[t] = 1 + (covered ? sum_c score_part + b2 : 0) ----------------
__global__ __launch_bounds__(256) void factor_kernel(const float* __restrict__ score_part,
                                                     const float* __restrict__ b2,
                                                     const int* __restrict__ sid_arr,
                                                     float* __restrict__ factor) {
  int t = blockIdx.x * 256 + threadIdx.x;
  if (t >= BB * TT) return;
  float s = b2[0];
#pragma unroll
  for (int c = 0; c < 8; ++c) s += score_part[(size_t)c * (BB * TT) + t];
  factor[t] = (sid_arr[t] >= 0) ? (1.0f + s) : 1.0f;
}

// ---------------- K9: out = h * factor[row] ----------------
__global__ __launch_bounds__(256) void scale_kernel(const float* __restrict__ h,
                                                    const float* __restrict__ factor,
                                                    float* __restrict__ out) {
  const float4* h4 = (const float4*)h;
  float4* o4 = (float4*)out;
  int idx = blockIdx.x * 256 + threadIdx.x;           // float4 index
  int total = BB * TT * (HH / 4);                     // 8.39M
  for (int e = idx; e < total; e += 2048 * 256) {
    float f = factor[e >> 8];                         // 256 float4 per row
    float4 v = h4[e];
    v.x *= f; v.y *= f; v.z *= f; v.w *= f;
    o4[e] = v;
  }
}

extern "C" void kernel_launch(void* const* d_in, const int* in_sizes, int n_in,
                              void* d_out, int out_size, void* d_ws, size_t ws_size,
                              hipStream_t stream) {
  const float* h        = (const float*)d_in[0];
  const int*   bounds   = (const int*)d_in[1];
  const float* in_proj_w = (const float*)d_in[2];
  const float* in_proj_b = (const float*)d_in[3];
  const float* out_w    = (const float*)d_in[4];
  const float* out_b    = (const float*)d_in[5];
  const float* w1       = (const float*)d_in[6];
  const float* b1       = (const float*)d_in[7];
  const float* w2       = (const float*)d_in[8];
  const float* b2       = (const float*)d_in[9];
  float* out = (float*)d_out;

  char* ws = (char*)d_ws;
  float* sent  = (float*)(ws);                        // 2 MB
  float* qkv   = (float*)(ws + (2ull << 20));         // 6 MB
  float* ctx   = (float*)(ws + (8ull << 20));         // 2 MB
  float* att   = (float*)(ws + (10ull << 20));        // 2 MB
  float* cbuf  = (float*)(ws + (12ull << 20));        // 2 MB
  int*   sid   = (int*)(ws + (14ull << 20));          // 128 KB
  float* spart = (float*)(ws + (15ull << 20));        // 8*32768 f32 = 1 MB
  float* factor = (float*)(ws + (16ull << 20));       // 128 KB

  pool_kernel<<<BB * SS, 256, 0, stream>>>(h, bounds, sent);
  sid_kernel<<<(BB * TT) / 256, 256, 0, stream>>>(bounds, sid);
  // qkv = sent @ in_proj_w^T + in_proj_b   (512 x 3072, K=1024)
  gemm_bt_bias<<<dim3(4, 24), 256, 0, stream>>>(sent, HH, in_proj_w, HH, in_proj_b, qkv, 3 * HH, HH);
  attn_kernel<<<BB * NHH, 256, 0, stream>>>(qkv, ctx);
  // attended = ctx @ out_w^T + out_b       (512 x 1024, K=1024)
  gemm_bt_bias<<<dim3(4, 8), 256, 0, stream>>>(ctx, HH, out_w, HH, out_b, att, HH, HH);
  // c = attended @ w1b^T + b1              (512 x 1024, K=1024), w1b = w1[:, H:]
  gemm_bt_bias<<<dim3(4, 8), 256, 0, stream>>>(att, HH, w1 + HH, 2 * HH, b1, cbuf, HH, HH);
  // big GEMM partial scores: 2048 blocks (256 M-tiles x 8 N-chunks)
  score_partial<<<2048, 256, 0, stream>>>(h, cbuf, w1, w2, sid, spart);
  factor_kernel<<<(BB * TT) / 256, 256, 0, stream>>>(spart, b2, sid, factor);
  scale_kernel<<<2048, 256, 0, stream>>>(h, factor, out);
}

// Round 4
// 344.008 us; speedup vs baseline: 2.1089x; 1.4977x over previous
//
#include <hip/hip_runtime.h>
#include <stdint.h>

// Problem constants
#define BB 8
#define TT 4096
#define HH 1024
#define SS 64
#define NHH 16
#define DHH 64

typedef __attribute__((ext_vector_type(8))) short short8;
typedef __attribute__((ext_vector_type(8))) unsigned short ushortx8;
typedef __attribute__((ext_vector_type(4))) float f32x4;
typedef unsigned short u16;

#define GLOAD16(gp, lp)                                                   \
  __builtin_amdgcn_global_load_lds(                                      \
      (const __attribute__((address_space(1))) void*)(gp),               \
      (__attribute__((address_space(3))) void*)(lp), 16, 0, 0)

__device__ __forceinline__ u16 f2bf(float f) {
  union { float f; uint32_t u; } v;
  v.f = f;
  uint32_t u = v.u;
  uint32_t r = u + 0x7fffu + ((u >> 16) & 1u);
  return (u16)(r >> 16);
}

// Stage a 128-row x 64-col f32 tile (row stride ld) into swizzled bf16 LDS.
// LDS layout: row*64 + (slot ^ (row&7))*8, slot = k/8 (8 slots of 8 bf16 = 16B).
__device__ __forceinline__ void stage_tile(u16* lds, const float* src, int ld, int tid) {
#pragma unroll
  for (int q = 0; q < 4; ++q) {
    int slot_id = tid + (q << 8);
    int row = slot_id >> 3;
    int sl = slot_id & 7;
    const float* p = src + (size_t)row * ld + (sl << 3);
    float4 x0 = *(const float4*)(p);
    float4 x1 = *(const float4*)(p + 4);
    ushortx8 o;
    o[0] = f2bf(x0.x); o[1] = f2bf(x0.y); o[2] = f2bf(x0.z); o[3] = f2bf(x0.w);
    o[4] = f2bf(x1.x); o[5] = f2bf(x1.y); o[6] = f2bf(x1.z); o[7] = f2bf(x1.w);
    *(ushortx8*)(&lds[(row << 6) + (((sl ^ (row & 7)) << 3))]) = o;
  }
}

// ---------------- conv: f32 matrix -> tiled pre-swizzled bf16 ----------------
// One block per 128x64 tile. dst tile layout byte-identical to the LDS layout
// stage_tile produced, so MFMA fragment reads are unchanged.
__global__ __launch_bounds__(256) void conv_tile_kernel(const float* __restrict__ src,
                                                        int ld, int ntile_k,
                                                        u16* __restrict__ dst) {
  int bid = blockIdx.x;
  int rt = bid / ntile_k;        // row-tile (128 rows)
  int kt = bid - rt * ntile_k;   // k-tile (64 cols)
  const float* s0 = src + (size_t)rt * 128 * ld + kt * 64;
  u16* d0 = dst + (size_t)bid * 8192;
  int tid = threadIdx.x;
#pragma unroll
  for (int q = 0; q < 4; ++q) {
    int slot_id = tid + (q << 8);
    int row = slot_id >> 3;
    int sl = slot_id & 7;
    const float* p = s0 + (size_t)row * ld + (sl << 3);
    float4 x0 = *(const float4*)(p);
    float4 x1 = *(const float4*)(p + 4);
    ushortx8 o;
    o[0] = f2bf(x0.x); o[1] = f2bf(x0.y); o[2] = f2bf(x0.z); o[3] = f2bf(x0.w);
    o[4] = f2bf(x1.x); o[5] = f2bf(x1.y); o[6] = f2bf(x1.z); o[7] = f2bf(x1.w);
    *(ushortx8*)(&d0[(row << 6) + (((sl ^ (row & 7)) << 3))]) = o;
  }
}

// ---------------- K1: sentence mean pooling (float4 + 4 accumulators) ----------------
__global__ __launch_bounds__(256) void pool_kernel(const float* __restrict__ h,
                                                   const int* __restrict__ bounds,
                                                   float* __restrict__ sent) {
  int bs = blockIdx.x;           // b*64 + s
  int b = bs >> 6;
  int start = bounds[bs * 2];
  int end = bounds[bs * 2 + 1];
  int lo = max(start, 0), hi = min(end, TT);
  int cnt = max(hi - lo, 0);
  float inv = 1.0f / (float)max(cnt, 1);
  int tid = threadIdx.x;  // one float4 column group per thread
  const float4* h4 = (const float4*)(h) + (size_t)b * TT * 256 + tid;
  float4 a0 = {0, 0, 0, 0}, a1 = {0, 0, 0, 0}, a2 = {0, 0, 0, 0}, a3 = {0, 0, 0, 0};
  int t = lo;
  for (; t + 4 <= hi; t += 4) {
    float4 v0 = h4[(size_t)(t + 0) * 256];
    float4 v1 = h4[(size_t)(t + 1) * 256];
    float4 v2 = h4[(size_t)(t + 2) * 256];
    float4 v3 = h4[(size_t)(t + 3) * 256];
    a0.x += v0.x; a0.y += v0.y; a0.z += v0.z; a0.w += v0.w;
    a1.x += v1.x; a1.y += v1.y; a1.z += v1.z; a1.w += v1.w;
    a2.x += v2.x; a2.y += v2.y; a2.z += v2.z; a2.w += v2.w;
    a3.x += v3.x; a3.y += v3.y; a3.z += v3.z; a3.w += v3.w;
  }
  for (; t < hi; ++t) {
    float4 v0 = h4[(size_t)t * 256];
    a0.x += v0.x; a0.y += v0.y; a0.z += v0.z; a0.w += v0.w;
  }
  float4 r;
  r.x = (a0.x + a1.x + a2.x + a3.x) * inv;
  r.y = (a0.y + a1.y + a2.y + a3.y) * inv;
  r.z = (a0.z + a1.z + a2.z + a3.z) * inv;
  r.w = (a0.w + a1.w + a2.w + a3.w) * inv;
  ((float4*)sent)[(size_t)bs * 256 + tid] = r;
}

// ---------------- K2: sentence id per token ----------------
__global__ __launch_bounds__(256) void sid_kernel(const int* __restrict__ bounds,
                                                  int* __restrict__ sid) {
  int idx = blockIdx.x * 256 + threadIdx.x;  // B*T
  if (idx >= BB * TT) return;
  int b = idx >> 12, t = idx & (TT - 1);
  int r = -1;
  for (int s = 0; s < SS; ++s) {
    int st = bounds[(b * SS + s) * 2], en = bounds[(b * SS + s) * 2 + 1];
    if (t >= st && t < en) { r = s; break; }
  }
  sid[idx] = r;
}

// ---------------- C init: C[row][col] = bias[col] ----------------
__global__ __launch_bounds__(256) void init_bias_kernel(const float* __restrict__ bias,
                                                        float* __restrict__ C, int ldc) {
  int col = blockIdx.x * 256 + threadIdx.x;
  int row = blockIdx.y;
  C[(size_t)row * ldc + col] = bias[col];
}

// ---------------- C = A @ B^T (+= via atomics), K-split over blockIdx.z ----------------
__global__ __launch_bounds__(256) void gemm_bt_atomic(const float* __restrict__ A, int lda,
                                                      const float* __restrict__ Bm, int ldb,
                                                      float* __restrict__ C, int ldc,
                                                      int kper) {
  __shared__ u16 As[128 * 64];
  __shared__ u16 Bs[128 * 64];
  int tid = threadIdx.x;
  int m0 = blockIdx.x * 128, n0 = blockIdx.y * 128;
  int kbeg = blockIdx.z * kper;
  f32x4 acc[4][4] = {};

  for (int k0 = kbeg; k0 < kbeg + kper; k0 += 64) {
    __syncthreads();
    stage_tile(As, A + (size_t)m0 * lda + k0, lda, tid);
    stage_tile(Bs, Bm + (size_t)n0 * ldb + k0, ldb, tid);
    __syncthreads();
    int lane = tid & 63, wid = tid >> 6;
    int wm = wid >> 1, wn = wid & 1;
    int lr = lane & 15, lg = lane >> 4;
#pragma unroll
    for (int kk = 0; kk < 2; ++kk) {
      short8 af[4], bfr[4];
#pragma unroll
      for (int i = 0; i < 4; ++i) {
        int arow = wm * 64 + i * 16 + lr;
        int aslot = (kk * 4 + lg) ^ (arow & 7);
        af[i] = *(const short8*)(&As[(arow << 6) + (aslot << 3)]);
        int brow = wn * 64 + i * 16 + lr;
        int bslot = (kk * 4 + lg) ^ (brow & 7);
        bfr[i] = *(const short8*)(&Bs[(brow << 6) + (bslot << 3)]);
      }
#pragma unroll
      for (int i = 0; i < 4; ++i)
#pragma unroll
        for (int j = 0; j < 4; ++j)
          acc[i][j] = __builtin_amdgcn_mfma_f32_16x16x32_bf16(af[i], bfr[j], acc[i][j], 0, 0, 0);
    }
  }

  int lane = tid & 63, wid = tid >> 6;
  int wm = wid >> 1, wn = wid & 1;
  int lr = lane & 15, lg = lane >> 4;
#pragma unroll
  for (int i = 0; i < 4; ++i)
#pragma unroll
    for (int j = 0; j < 4; ++j)
#pragma unroll
      for (int r = 0; r < 4; ++r) {
        int row = m0 + wm * 64 + i * 16 + lg * 4 + r;
        int col = n0 + wn * 64 + j * 16 + lr;
        atomicAdd(&C[(size_t)row * ldc + col], acc[i][j][r]);
      }
}

// ---------------- K4: attention over S=64 per (b, head) ----------------
__global__ __launch_bounds__(256) void attn_kernel(const float* __restrict__ qkv,
                                                   float* __restrict__ ctx) {
  int bh = blockIdx.x;
  int b = bh >> 4, nh = bh & 15;
  __shared__ float q[64][64], k[64][64], v[64][64], s[64][64];
  int tid = threadIdx.x;
  const float* base = qkv + (size_t)b * SS * 3072 + nh * 64;
  for (int e = tid; e < 4096; e += 256) {
    int i = e >> 6, d = e & 63;
    q[i][d] = base[(size_t)i * 3072 + d];
    k[i][d] = base[(size_t)i * 3072 + 1024 + d];
    v[i][d] = base[(size_t)i * 3072 + 2048 + d];
  }
  __syncthreads();
  for (int e = tid; e < 4096; e += 256) {
    int i = e >> 6, j = e & 63;
    float acc = 0.f;
#pragma unroll 8
    for (int d = 0; d < 64; ++d) acc += q[i][d] * k[j][d];
    s[i][j] = acc * 0.125f;  // 1/sqrt(64)
  }
  __syncthreads();
  {
    // 4 lanes per row (lanes 4r..4r+3 are in the same wave)
    int r = tid >> 2, sub = tid & 3;
    int j0 = sub * 16;
    float m = -1e30f;
#pragma unroll
    for (int j = 0; j < 16; ++j) m = fmaxf(m, s[r][j0 + j]);
    m = fmaxf(m, __shfl_xor(m, 1));
    m = fmaxf(m, __shfl_xor(m, 2));
    float sum = 0.f;
#pragma unroll
    for (int j = 0; j < 16; ++j) {
      float e_ = __expf(s[r][j0 + j] - m);
      s[r][j0 + j] = e_;
      sum += e_;
    }
    sum += __shfl_xor(sum, 1);
    sum += __shfl_xor(sum, 2);
    float inv = 1.0f / sum;
#pragma unroll
    for (int j = 0; j < 16; ++j) s[r][j0 + j] *= inv;
  }
  __syncthreads();
  for (int e = tid; e < 4096; e += 256) {
    int i = e >> 6, d = e & 63;
    float acc = 0.f;
#pragma unroll 8
    for (int j = 0; j < 64; ++j) acc += s[i][j] * v[j][d];
    ctx[((size_t)b * SS + i) * HH + nh * 64 + d] = acc;
  }
}

// ---------------- K7: partial score for one (M-tile, N-chunk) ----------------
// grid: 2048 blocks; mt = bid>>3 (M-tile of 128 rows), c = bid&7 (N-chunk of 128 cols).
// Operands are pre-converted tiled/swizzled bf16; staging via global_load_lds (16B).
__global__ __launch_bounds__(256) void score_partial(const u16* __restrict__ hbf,
                                                     const u16* __restrict__ wbf,
                                                     const float* __restrict__ cbuf,
                                                     const float* __restrict__ w2,
                                                     const int* __restrict__ sid_arr,
                                                     float* __restrict__ score_part) {
  __shared__ u16 As[8192];
  __shared__ u16 Bs[8192];
  __shared__ float w2_lds[128];
  __shared__ int sid_lds[128];
  __shared__ float red[128];

  int tid = threadIdx.x;
  int bid = blockIdx.x;
  int mt = bid >> 3;
  int c = bid & 7;
  int n0 = c * 128;
  size_t g0 = (size_t)mt * 128;  // global token row
  int b = (int)(g0 >> 12);       // / T
  const u16* asrc = hbf + (size_t)mt * 16 * 8192;
  const u16* bsrc = wbf + (size_t)c * 16 * 8192;

  if (tid < 128) {
    w2_lds[tid] = w2[n0 + tid];
    sid_lds[tid] = sid_arr[g0 + tid];
    red[tid] = 0.f;
  }

  int lane = tid & 63, wid = tid >> 6;
  int wv = wid, ln = lane;
  int wm = wid >> 1, wn = wid & 1;
  int lr = lane & 15, lg = lane >> 4;

  f32x4 acc[4][4] = {};
  for (int kt = 0; kt < 16; ++kt) {
    __syncthreads();  // protect previous iteration's LDS reads
    const u16* at = asrc + kt * 8192;
    const u16* bt = bsrc + kt * 8192;
#pragma unroll
    for (int q = 0; q < 4; ++q) {
      int off = q * 2048 + wv * 512 + ln * 8;  // u16 units; lane covers 16 B
      GLOAD16(at + off, &As[q * 2048 + wv * 512]);
      GLOAD16(bt + off, &Bs[q * 2048 + wv * 512]);
    }
    __syncthreads();  // compiler drains vmcnt(0) before barrier -> tiles ready
#pragma unroll
    for (int kk = 0; kk < 2; ++kk) {
      short8 af[4], bfr[4];
#pragma unroll
      for (int i = 0; i < 4; ++i) {
        int arow = wm * 64 + i * 16 + lr;
        int aslot = (kk * 4 + lg) ^ (arow & 7);
        af[i] = *(const short8*)(&As[(arow << 6) + (aslot << 3)]);
        int brow = wn * 64 + i * 16 + lr;
        int bslot = (kk * 4 + lg) ^ (brow & 7);
        bfr[i] = *(const short8*)(&Bs[(brow << 6) + (bslot << 3)]);
      }
#pragma unroll
      for (int i = 0; i < 4; ++i)
#pragma unroll
        for (int j = 0; j < 4; ++j)
          acc[i][j] = __builtin_amdgcn_mfma_f32_16x16x32_bf16(af[i], bfr[j], acc[i][j], 0, 0, 0);
    }
  }

  // score epilogue: sp = sum_j w2[j] * relu(u + c[sid, j]) over this chunk's 128 cols
  float sp[4][4];
#pragma unroll
  for (int i = 0; i < 4; ++i) {
#pragma unroll
    for (int r = 0; r < 4; ++r) {
      int rowl = wm * 64 + i * 16 + lg * 4 + r;
      int s = sid_lds[rowl];
      int sc = s < 0 ? 0 : s;
      const float* crow = cbuf + ((size_t)b * SS + sc) * HH + n0;
      float accs = 0.f;
#pragma unroll
      for (int j = 0; j < 4; ++j) {
        int coll = wn * 64 + j * 16 + lr;
        float t = acc[i][j][r] + crow[coll];
        if (t > 0.f) accs += t * w2_lds[coll];
      }
      sp[i][r] = accs;
    }
  }

  // reduce across the 16 lanes of each lane-group
#pragma unroll
  for (int i = 0; i < 4; ++i)
#pragma unroll
    for (int r = 0; r < 4; ++r) {
      float v = sp[i][r];
      v += __shfl_xor(v, 1);
      v += __shfl_xor(v, 2);
      v += __shfl_xor(v, 4);
      v += __shfl_xor(v, 8);
      sp[i][r] = v;
    }
  if (lr == 0) {
#pragma unroll
    for (int i = 0; i < 4; ++i)
#pragma unroll
      for (int r = 0; r < 4; ++r)
        atomicAdd(&red[wm * 64 + i * 16 + lg * 4 + r], sp[i][r]);
  }
  __syncthreads();
  if (tid < 128) score_part[(size_t)c * (BB * TT) + g0 + tid] = red[tid];
}

// ---------------- K9: out = h * (1 + covered*(sum_c spart + b2)) ----------------
__global__ __launch_bounds__(256) void scale_kernel(const float* __restrict__ h,
                                                    const float* __restrict__ score_part,
                                                    const float* __restrict__ b2,
                                                    const int* __restrict__ sid_arr,
                                                    float* __restrict__ out) {
  __shared__ float fac[16];
  int tid = threadIdx.x;
  int r0 = blockIdx.x * 16;
  if (tid < 16) {
    int t = r0 + tid;
    float s = b2[0];
#pragma unroll
    for (int c = 0; c < 8; ++c) s += score_part[(size_t)c * (BB * TT) + t];
    fac[tid] = (sid_arr[t] >= 0) ? (1.0f + s) : 1.0f;
  }
  __syncthreads();
  const float4* h4 = (const float4*)h + (size_t)r0 * 256;
  float4* o4 = (float4*)out + (size_t)r0 * 256;
  for (int e = tid; e < 16 * 256; e += 256) {
    float f = fac[e >> 8];
    float4 v = h4[e];
    v.x *= f; v.y *= f; v.z *= f; v.w *= f;
    o4[e] = v;
  }
}

extern "C" void kernel_launch(void* const* d_in, const int* in_sizes, int n_in,
                              void* d_out, int out_size, void* d_ws, size_t ws_size,
                              hipStream_t stream) {
  const float* h        = (const float*)d_in[0];
  const int*   bounds   = (const int*)d_in[1];
  const float* in_proj_w = (const float*)d_in[2];
  const float* in_proj_b = (const float*)d_in[3];
  const float* out_w    = (const float*)d_in[4];
  const float* out_b    = (const float*)d_in[5];
  const float* w1       = (const float*)d_in[6];
  const float* b1       = (const float*)d_in[7];
  const float* w2       = (const float*)d_in[8];
  const float* b2       = (const float*)d_in[9];
  float* out = (float*)d_out;

  char* ws = (char*)d_ws;
  float* sent  = (float*)(ws);                        // 2 MB
  float* qkv   = (float*)(ws + (2ull << 20));         // 6 MB
  float* ctx   = (float*)(ws + (8ull << 20));         // 2 MB
  float* att   = (float*)(ws + (10ull << 20));        // 2 MB
  float* cbuf  = (float*)(ws + (12ull << 20));        // 2 MB
  int*   sid   = (int*)(ws + (14ull << 20));          // 128 KB
  float* spart = (float*)(ws + (15ull << 20));        // 1 MB
  u16*   hbf   = (u16*)(ws + (16ull << 20));          // 256*16 tiles * 16 KB = 64 MB
  u16*   wbf   = (u16*)(ws + (80ull << 20));          // 8*16 tiles * 16 KB = 2 MB

  // pre-convert operands of the big GEMM to tiled/swizzled bf16
  conv_tile_kernel<<<256 * 16, 256, 0, stream>>>(h, HH, 16, hbf);
  conv_tile_kernel<<<8 * 16, 256, 0, stream>>>(w1, 2 * HH, 16, wbf);  // w1a: k<1024

  pool_kernel<<<BB * SS, 256, 0, stream>>>(h, bounds, sent);
  sid_kernel<<<(BB * TT) / 256, 256, 0, stream>>>(bounds, sid);

  // qkv = sent @ in_proj_w^T + in_proj_b   (512 x 3072, K=1024), K-split x4
  init_bias_kernel<<<dim3(12, 512), 256, 0, stream>>>(in_proj_b, qkv, 3 * HH);
  gemm_bt_atomic<<<dim3(4, 24, 4), 256, 0, stream>>>(sent, HH, in_proj_w, HH, qkv, 3 * HH, 256);
  attn_kernel<<<BB * NHH, 256, 0, stream>>>(qkv, ctx);
  // attended = ctx @ out_w^T + out_b       (512 x 1024, K=1024), K-split x4
  init_bias_kernel<<<dim3(4, 512), 256, 0, stream>>>(out_b, att, HH);
  gemm_bt_atomic<<<dim3(4, 8, 4), 256, 0, stream>>>(ctx, HH, out_w, HH, att, HH, 256);
  // c = attended @ w1b^T + b1              (512 x 1024, K=1024), w1b = w1[:, H:]
  init_bias_kernel<<<dim3(4, 512), 256, 0, stream>>>(b1, cbuf, HH);
  gemm_bt_atomic<<<dim3(4, 8, 4), 256, 0, stream>>>(att, HH, w1 + HH, 2 * HH, cbuf, HH, 256);

  // big GEMM partial scores: 2048 blocks (256 M-tiles x 8 N-chunks)
  score_partial<<<2048, 256, 0, stream>>>(hbf, wbf, cbuf, w2, sid, spart);
  scale_kernel<<<2048, 256, 0, stream>>>(h, spart, b2, sid, out);
}

// Round 5
// 326.099 us; speedup vs baseline: 2.2247x; 1.0549x over previous
//
#include <hip/hip_runtime.h>
#include <stdint.h>

// Problem constants
#define BB 8
#define TT 4096
#define HH 1024
#define SS 64
#define NHH 16
#define DHH 64

typedef __attribute__((ext_vector_type(8))) short short8;
typedef __attribute__((ext_vector_type(8))) unsigned short ushortx8;
typedef __attribute__((ext_vector_type(4))) float f32x4;
typedef unsigned short u16;

#define GLOAD16(gp, lp)                                                   \
  __builtin_amdgcn_global_load_lds(                                      \
      (const __attribute__((address_space(1))) void*)(gp),               \
      (__attribute__((address_space(3))) void*)(lp), 16, 0, 0)

__device__ __forceinline__ u16 f2bf(float f) {
  union { float f; uint32_t u; } v;
  v.f = f;
  uint32_t u = v.u;
  uint32_t r = u + 0x7fffu + ((u >> 16) & 1u);
  return (u16)(r >> 16);
}

__device__ __forceinline__ float bf2f(u16 b) {
  union { uint32_t u; float f; } v;
  v.u = ((uint32_t)b) << 16;
  return v.f;
}

// Stage a 128-row x 64-col f32 tile (row stride ld) into swizzled bf16 LDS.
// LDS layout: row*64 + (slot ^ (row&7))*8, slot = k/8 (8 slots of 8 bf16 = 16B).
__device__ __forceinline__ void stage_tile(u16* lds, const float* src, int ld, int tid) {
#pragma unroll
  for (int q = 0; q < 4; ++q) {
    int slot_id = tid + (q << 8);
    int row = slot_id >> 3;
    int sl = slot_id & 7;
    const float* p = src + (size_t)row * ld + (sl << 3);
    float4 x0 = *(const float4*)(p);
    float4 x1 = *(const float4*)(p + 4);
    ushortx8 o;
    o[0] = f2bf(x0.x); o[1] = f2bf(x0.y); o[2] = f2bf(x0.z); o[3] = f2bf(x0.w);
    o[4] = f2bf(x1.x); o[5] = f2bf(x1.y); o[6] = f2bf(x1.z); o[7] = f2bf(x1.w);
    *(ushortx8*)(&lds[(row << 6) + (((sl ^ (row & 7)) << 3))]) = o;
  }
}

// ---------------- conv: f32 matrix -> tiled pre-swizzled bf16 ----------------
__global__ __launch_bounds__(256) void conv_tile_kernel(const float* __restrict__ src,
                                                        int ld, int ntile_k,
                                                        u16* __restrict__ dst) {
  int bid = blockIdx.x;
  int rt = bid / ntile_k;        // row-tile (128 rows)
  int kt = bid - rt * ntile_k;   // k-tile (64 cols)
  const float* s0 = src + (size_t)rt * 128 * ld + kt * 64;
  u16* d0 = dst + (size_t)bid * 8192;
  int tid = threadIdx.x;
#pragma unroll
  for (int q = 0; q < 4; ++q) {
    int slot_id = tid + (q << 8);
    int row = slot_id >> 3;
    int sl = slot_id & 7;
    const float* p = s0 + (size_t)row * ld + (sl << 3);
    float4 x0 = *(const float4*)(p);
    float4 x1 = *(const float4*)(p + 4);
    ushortx8 o;
    o[0] = f2bf(x0.x); o[1] = f2bf(x0.y); o[2] = f2bf(x0.z); o[3] = f2bf(x0.w);
    o[4] = f2bf(x1.x); o[5] = f2bf(x1.y); o[6] = f2bf(x1.z); o[7] = f2bf(x1.w);
    *(ushortx8*)(&d0[(row << 6) + (((sl ^ (row & 7)) << 3))]) = o;
  }
}

// ---------------- K1: sentence mean pooling from tiled bf16 hbf ----------------
// block = one (b,s); thread pair (sg, half): sg = 8-col slot group, half splits tokens.
__global__ __launch_bounds__(256) void pool_bf_kernel(const u16* __restrict__ hbf,
                                                      const int* __restrict__ bounds,
                                                      float* __restrict__ sent) {
  int bs = blockIdx.x;           // b*64 + s
  int b = bs >> 6;
  int start = bounds[bs * 2];
  int end = bounds[bs * 2 + 1];
  int lo = max(start, 0), hi = min(end, TT);
  int cnt = max(hi - lo, 0);
  float inv = 1.0f / (float)max(cnt, 1);
  int tid = threadIdx.x;
  int sg = tid >> 1;             // 0..127 -> cols sg*8 .. sg*8+7
  int half = tid & 1;
  int kt = sg >> 3, slot = sg & 7;
  float a[8] = {};
  for (int t = lo + half; t < hi; t += 2) {
    int grow = b * TT + t;
    int rt = grow >> 7, r = grow & 127;
    const u16* tile = hbf + ((size_t)rt * 16 + kt) * 8192;
    ushortx8 v = *(const ushortx8*)(&tile[(r << 6) + ((slot ^ (r & 7)) << 3)]);
#pragma unroll
    for (int j = 0; j < 8; ++j) a[j] += bf2f(v[j]);
  }
#pragma unroll
  for (int j = 0; j < 8; ++j) a[j] += __shfl_xor(a[j], 1);
  if (half == 0) {
    float* d = sent + (size_t)bs * HH + sg * 8;
#pragma unroll
    for (int j = 0; j < 8; ++j) d[j] = a[j] * inv;
  }
}

// ---------------- setup: bias-init qkv/att/cbuf + sid, one grid-stride kernel ----------------
__global__ __launch_bounds__(256) void setup_misc(const float* __restrict__ ipb,
                                                  const float* __restrict__ outb,
                                                  const float* __restrict__ b1,
                                                  const int* __restrict__ bounds,
                                                  float* __restrict__ qkv,
                                                  float* __restrict__ att,
                                                  float* __restrict__ cbuf,
                                                  int* __restrict__ sid) {
  int idx = blockIdx.x * 256 + threadIdx.x;
  const int STR = 2048 * 256;
  for (int i = idx; i < 512 * 3072; i += STR) qkv[i] = ipb[i % 3072];
  for (int i = idx; i < 512 * 1024; i += STR) att[i] = outb[i & 1023];
  for (int i = idx; i < 512 * 1024; i += STR) cbuf[i] = b1[i & 1023];
  if (idx < BB * TT) {
    int b = idx >> 12, t = idx & (TT - 1);
    int r = -1;
    for (int s = 0; s < SS; ++s) {
      int st = bounds[(b * SS + s) * 2], en = bounds[(b * SS + s) * 2 + 1];
      if (t >= st && t < en) { r = s; break; }
    }
    sid[idx] = r;
  }
}

// ---------------- C += A @ B^T via atomics, K-split over blockIdx.z ----------------
__global__ __launch_bounds__(256) void gemm_bt_atomic(const float* __restrict__ A, int lda,
                                                      const float* __restrict__ Bm, int ldb,
                                                      float* __restrict__ C, int ldc,
                                                      int kper) {
  __shared__ u16 As[128 * 64];
  __shared__ u16 Bs[128 * 64];
  int tid = threadIdx.x;
  int m0 = blockIdx.x * 128, n0 = blockIdx.y * 128;
  int kbeg = blockIdx.z * kper;
  f32x4 acc[4][4] = {};

  for (int k0 = kbeg; k0 < kbeg + kper; k0 += 64) {
    __syncthreads();
    stage_tile(As, A + (size_t)m0 * lda + k0, lda, tid);
    stage_tile(Bs, Bm + (size_t)n0 * ldb + k0, ldb, tid);
    __syncthreads();
    int lane = tid & 63, wid = tid >> 6;
    int wm = wid >> 1, wn = wid & 1;
    int lr = lane & 15, lg = lane >> 4;
#pragma unroll
    for (int kk = 0; kk < 2; ++kk) {
      short8 af[4], bfr[4];
#pragma unroll
      for (int i = 0; i < 4; ++i) {
        int arow = wm * 64 + i * 16 + lr;
        int aslot = (kk * 4 + lg) ^ (arow & 7);
        af[i] = *(const short8*)(&As[(arow << 6) + (aslot << 3)]);
        int brow = wn * 64 + i * 16 + lr;
        int bslot = (kk * 4 + lg) ^ (brow & 7);
        bfr[i] = *(const short8*)(&Bs[(brow << 6) + (bslot << 3)]);
      }
#pragma unroll
      for (int i = 0; i < 4; ++i)
#pragma unroll
        for (int j = 0; j < 4; ++j)
          acc[i][j] = __builtin_amdgcn_mfma_f32_16x16x32_bf16(af[i], bfr[j], acc[i][j], 0, 0, 0);
    }
  }

  int lane = tid & 63, wid = tid >> 6;
  int wm = wid >> 1, wn = wid & 1;
  int lr = lane & 15, lg = lane >> 4;
#pragma unroll
  for (int i = 0; i < 4; ++i)
#pragma unroll
    for (int j = 0; j < 4; ++j)
#pragma unroll
      for (int r = 0; r < 4; ++r) {
        int row = m0 + wm * 64 + i * 16 + lg * 4 + r;
        int col = n0 + wn * 64 + j * 16 + lr;
        atomicAdd(&C[(size_t)row * ldc + col], acc[i][j][r]);
      }
}

// ---------------- K4: attention over S=64 per (b, head) ----------------
__global__ __launch_bounds__(256) void attn_kernel(const float* __restrict__ qkv,
                                                   float* __restrict__ ctx) {
  int bh = blockIdx.x;
  int b = bh >> 4, nh = bh & 15;
  __shared__ float q[64][64], k[64][64], v[64][64], s[64][64];
  int tid = threadIdx.x;
  const float* base = qkv + (size_t)b * SS * 3072 + nh * 64;
  for (int e = tid; e < 4096; e += 256) {
    int i = e >> 6, d = e & 63;
    q[i][d] = base[(size_t)i * 3072 + d];
    k[i][d] = base[(size_t)i * 3072 + 1024 + d];
    v[i][d] = base[(size_t)i * 3072 + 2048 + d];
  }
  __syncthreads();
  for (int e = tid; e < 4096; e += 256) {
    int i = e >> 6, j = e & 63;
    float acc = 0.f;
#pragma unroll 8
    for (int d = 0; d < 64; ++d) acc += q[i][d] * k[j][d];
    s[i][j] = acc * 0.125f;  // 1/sqrt(64)
  }
  __syncthreads();
  {
    int r = tid >> 2, sub = tid & 3;
    int j0 = sub * 16;
    float m = -1e30f;
#pragma unroll
    for (int j = 0; j < 16; ++j) m = fmaxf(m, s[r][j0 + j]);
    m = fmaxf(m, __shfl_xor(m, 1));
    m = fmaxf(m, __shfl_xor(m, 2));
    float sum = 0.f;
#pragma unroll
    for (int j = 0; j < 16; ++j) {
      float e_ = __expf(s[r][j0 + j] - m);
      s[r][j0 + j] = e_;
      sum += e_;
    }
    sum += __shfl_xor(sum, 1);
    sum += __shfl_xor(sum, 2);
    float inv = 1.0f / sum;
#pragma unroll
    for (int j = 0; j < 16; ++j) s[r][j0 + j] *= inv;
  }
  __syncthreads();
  for (int e = tid; e < 4096; e += 256) {
    int i = e >> 6, d = e & 63;
    float acc = 0.f;
#pragma unroll 8
    for (int j = 0; j < 64; ++j) acc += s[i][j] * v[j][d];
    ctx[((size_t)b * SS + i) * HH + nh * 64 + d] = acc;
  }
}

// ---------------- K7: partial score for one (M-tile, N-chunk) ----------------
// XCD-grouped swizzle: x = bid&7 (~XCD id), g = bid>>3.
// mt = x*32 + (g>>3), c = g&7  =>  the 8 c-chunks of one M-tile run as 8
// consecutive blocks on ONE XCD: hbf M-tile fetched once to that L2, reused x8;
// wbf (2 MB total) stays L2-resident on every XCD.
__global__ __launch_bounds__(256) void score_partial(const u16* __restrict__ hbf,
                                                     const u16* __restrict__ wbf,
                                                     const float* __restrict__ cbuf,
                                                     const float* __restrict__ w2,
                                                     const int* __restrict__ sid_arr,
                                                     float* __restrict__ score_part) {
  __shared__ u16 As[8192];
  __shared__ u16 Bs[8192];
  __shared__ float w2_lds[128];
  __shared__ int sid_lds[128];
  __shared__ float red[128];

  int tid = threadIdx.x;
  int bid = blockIdx.x;
  int x = bid & 7;
  int g = bid >> 3;
  int mt = x * 32 + (g >> 3);
  int c = g & 7;
  int n0 = c * 128;
  size_t g0 = (size_t)mt * 128;  // global token row
  int b = (int)(g0 >> 12);       // / T
  const u16* asrc = hbf + (size_t)mt * 16 * 8192;
  const u16* bsrc = wbf + (size_t)c * 16 * 8192;

  if (tid < 128) {
    w2_lds[tid] = w2[n0 + tid];
    sid_lds[tid] = sid_arr[g0 + tid];
    red[tid] = 0.f;
  }

  int lane = tid & 63, wid = tid >> 6;
  int wv = wid, ln = lane;
  int wm = wid >> 1, wn = wid & 1;
  int lr = lane & 15, lg = lane >> 4;

  f32x4 acc[4][4] = {};
  for (int kt = 0; kt < 16; ++kt) {
    __syncthreads();  // protect previous iteration's LDS reads
    const u16* at = asrc + kt * 8192;
    const u16* bt = bsrc + kt * 8192;
#pragma unroll
    for (int q = 0; q < 4; ++q) {
      int off = q * 2048 + wv * 512 + ln * 8;  // u16 units; lane covers 16 B
      GLOAD16(at + off, &As[q * 2048 + wv * 512]);
      GLOAD16(bt + off, &Bs[q * 2048 + wv * 512]);
    }
    __syncthreads();  // compiler drains vmcnt(0) before barrier -> tiles ready
#pragma unroll
    for (int kk = 0; kk < 2; ++kk) {
      short8 af[4], bfr[4];
#pragma unroll
      for (int i = 0; i < 4; ++i) {
        int arow = wm * 64 + i * 16 + lr;
        int aslot = (kk * 4 + lg) ^ (arow & 7);
        af[i] = *(const short8*)(&As[(arow << 6) + (aslot << 3)]);
        int brow = wn * 64 + i * 16 + lr;
        int bslot = (kk * 4 + lg) ^ (brow & 7);
        bfr[i] = *(const short8*)(&Bs[(brow << 6) + (bslot << 3)]);
      }
#pragma unroll
      for (int i = 0; i < 4; ++i)
#pragma unroll
        for (int j = 0; j < 4; ++j)
          acc[i][j] = __builtin_amdgcn_mfma_f32_16x16x32_bf16(af[i], bfr[j], acc[i][j], 0, 0, 0);
    }
  }

  // score epilogue: sp = sum_j w2[j] * relu(u + c[sid, j]) over this chunk's 128 cols
  float sp[4][4];
#pragma unroll
  for (int i = 0; i < 4; ++i) {
#pragma unroll
    for (int r = 0; r < 4; ++r) {
      int rowl = wm * 64 + i * 16 + lg * 4 + r;
      int s = sid_lds[rowl];
      int sc = s < 0 ? 0 : s;
      const float* crow = cbuf + ((size_t)b * SS + sc) * HH + n0;
      float accs = 0.f;
#pragma unroll
      for (int j = 0; j < 4; ++j) {
        int coll = wn * 64 + j * 16 + lr;
        float t = acc[i][j][r] + crow[coll];
        if (t > 0.f) accs += t * w2_lds[coll];
      }
      sp[i][r] = accs;
    }
  }

  // reduce across the 16 lanes of each lane-group
#pragma unroll
  for (int i = 0; i < 4; ++i)
#pragma unroll
    for (int r = 0; r < 4; ++r) {
      float v = sp[i][r];
      v += __shfl_xor(v, 1);
      v += __shfl_xor(v, 2);
      v += __shfl_xor(v, 4);
      v += __shfl_xor(v, 8);
      sp[i][r] = v;
    }
  if (lr == 0) {
#pragma unroll
    for (int i = 0; i < 4; ++i)
#pragma unroll
      for (int r = 0; r < 4; ++r)
        atomicAdd(&red[wm * 64 + i * 16 + lg * 4 + r], sp[i][r]);
  }
  __syncthreads();
  if (tid < 128) score_part[(size_t)c * (BB * TT) + g0 + tid] = red[tid];
}

// ---------------- K9: out = h * (1 + covered*(sum_c spart + b2)) ----------------
__global__ __launch_bounds__(256) void scale_kernel(const float* __restrict__ h,
                                                    const float* __restrict__ score_part,
                                                    const float* __restrict__ b2,
                                                    const int* __restrict__ sid_arr,
                                                    float* __restrict__ out) {
  __shared__ float fac[16];
  int tid = threadIdx.x;
  int r0 = blockIdx.x * 16;
  if (tid < 16) {
    int t = r0 + tid;
    float s = b2[0];
#pragma unroll
    for (int c = 0; c < 8; ++c) s += score_part[(size_t)c * (BB * TT) + t];
    fac[tid] = (sid_arr[t] >= 0) ? (1.0f + s) : 1.0f;
  }
  __syncthreads();
  const float4* h4 = (const float4*)h + (size_t)r0 * 256;
  float4* o4 = (float4*)out + (size_t)r0 * 256;
  for (int e = tid; e < 16 * 256; e += 256) {
    float f = fac[e >> 8];
    float4 v = h4[e];
    v.x *= f; v.y *= f; v.z *= f; v.w *= f;
    o4[e] = v;
  }
}

extern "C" void kernel_launch(void* const* d_in, const int* in_sizes, int n_in,
                              void* d_out, int out_size, void* d_ws, size_t ws_size,
                              hipStream_t stream) {
  const float* h        = (const float*)d_in[0];
  const int*   bounds   = (const int*)d_in[1];
  const float* in_proj_w = (const float*)d_in[2];
  const float* in_proj_b = (const float*)d_in[3];
  const float* out_w    = (const float*)d_in[4];
  const float* out_b    = (const float*)d_in[5];
  const float* w1       = (const float*)d_in[6];
  const float* b1       = (const float*)d_in[7];
  const float* w2       = (const float*)d_in[8];
  const float* b2       = (const float*)d_in[9];
  float* out = (float*)d_out;

  char* ws = (char*)d_ws;
  float* sent  = (float*)(ws);                        // 2 MB
  float* qkv   = (float*)(ws + (2ull << 20));         // 6 MB
  float* ctx   = (float*)(ws + (8ull << 20));         // 2 MB
  float* att   = (float*)(ws + (10ull << 20));        // 2 MB
  float* cbuf  = (float*)(ws + (12ull << 20));        // 2 MB
  int*   sid   = (int*)(ws + (14ull << 20));          // 128 KB
  float* spart = (float*)(ws + (15ull << 20));        // 1 MB
  u16*   hbf   = (u16*)(ws + (16ull << 20));          // 64 MB
  u16*   wbf   = (u16*)(ws + (80ull << 20));          // 2 MB

  // pre-convert operands of the big GEMM to tiled/swizzled bf16
  conv_tile_kernel<<<256 * 16, 256, 0, stream>>>(h, HH, 16, hbf);
  conv_tile_kernel<<<8 * 16, 256, 0, stream>>>(w1, 2 * HH, 16, wbf);  // w1a: k<1024

  pool_bf_kernel<<<BB * SS, 256, 0, stream>>>(hbf, bounds, sent);
  setup_misc<<<2048, 256, 0, stream>>>(in_proj_b, out_b, b1, bounds, qkv, att, cbuf, sid);

  // qkv = sent @ in_proj_w^T + in_proj_b   (512 x 3072, K=1024), K-split x4
  gemm_bt_atomic<<<dim3(4, 24, 4), 256, 0, stream>>>(sent, HH, in_proj_w, HH, qkv, 3 * HH, 256);
  attn_kernel<<<BB * NHH, 256, 0, stream>>>(qkv, ctx);
  // attended = ctx @ out_w^T + out_b       (512 x 1024, K=1024), K-split x4
  gemm_bt_atomic<<<dim3(4, 8, 4), 256, 0, stream>>>(ctx, HH, out_w, HH, att, HH, 256);
  // c = attended @ w1b^T + b1              (512 x 1024, K=1024), w1b = w1[:, H:]
  gemm_bt_atomic<<<dim3(4, 8, 4), 256, 0, stream>>>(att, HH, w1 + HH, 2 * HH, cbuf, HH, 256);

  // big GEMM partial scores: 2048 blocks, XCD-grouped (see score_partial comment)
  score_partial<<<2048, 256, 0, stream>>>(hbf, wbf, cbuf, w2, sid, spart);
  scale_kernel<<<2048, 256, 0, stream>>>(h, spart, b2, sid, out);
}